// Round 2
// baseline (90.195 us; speedup 1.0000x reference)
//
#include <hip/hip_runtime.h>
#include <math.h>

#define BZ 32
#define SRC_LEN 2048
#define DIM 1024
#define NCHUNK 32
#define CHUNK 64   // SRC_LEN / NCHUNK

__device__ inline float wave_reduce_sum(float v) {
#pragma unroll
    for (int off = 32; off > 0; off >>= 1) v += __shfl_xor(v, off, 64);
    return v;
}

// ---------------- kernel 1: proj[b][e] = sum_d tgt[b][d] * Wg[e][d] ----------
// grid 32 blocks (e-chunks of 32), 256 threads. Wg read exactly once.
__global__ __launch_bounds__(256) void k_proj(const float* __restrict__ tgt,
                                              const float* __restrict__ Wg,
                                              float* __restrict__ proj) {
    __shared__ float tg[32 * 129];   // padded stride 129 -> conflict-free
    __shared__ float wt[32 * 128];
    const int t = threadIdx.x;
    const int e0 = blockIdx.x * 32;
    const int b = t & 31;
    const int eg = t >> 5;           // 0..7, owns 4 e's
    float acc[4] = {0.f, 0.f, 0.f, 0.f};
    for (int d0 = 0; d0 < DIM; d0 += 128) {
        __syncthreads();
#pragma unroll
        for (int i = 0; i < 4; ++i) {
            int flat = t * 4 + i * 1024;
            int row = flat >> 7, col = flat & 127;
            float4 v = *(const float4*)&tgt[row * DIM + d0 + col];
            tg[row * 129 + col + 0] = v.x;
            tg[row * 129 + col + 1] = v.y;
            tg[row * 129 + col + 2] = v.z;
            tg[row * 129 + col + 3] = v.w;
        }
#pragma unroll
        for (int i = 0; i < 4; ++i) {
            int flat = t * 4 + i * 1024;
            int row = flat >> 7, col = flat & 127;
            *(float4*)&wt[row * 128 + col] = *(const float4*)&Wg[(size_t)(e0 + row) * DIM + d0 + col];
        }
        __syncthreads();
        for (int kk = 0; kk < 128; ++kk) {
            float tv = tg[b * 129 + kk];
#pragma unroll
            for (int i = 0; i < 4; ++i)
                acc[i] += tv * wt[(eg * 4 + i) * 128 + kk];
        }
    }
#pragma unroll
    for (int i = 0; i < 4; ++i)
        proj[b * DIM + e0 + eg * 4 + i] = acc[i];
}

// ---------------- kernel 2: flash pass over src (single read of 256 MB) -----
// grid = 32 b * 32 chunks = 1024 blocks, 256 threads = 4 waves.
// wave handles one s at a time: dot(proj, src[s]) -> online softmax + context.
__global__ __launch_bounds__(256) void k_flash(const float* __restrict__ src,
                                               const float* __restrict__ proj,
                                               const int* __restrict__ lens,
                                               float* __restrict__ scores,
                                               float* __restrict__ part_ml,
                                               float* __restrict__ part_c) {
    const int blk = blockIdx.x;
    const int b = blk >> 5;          // /32
    const int chunk = blk & 31;
    const int s0 = chunk * CHUNK;
    const int lane = threadIdx.x & 63;
    const int wave = threadIdx.x >> 6;
    const int len = lens[b];

    float4 pj[4];
#pragma unroll
    for (int j = 0; j < 4; ++j)
        pj[j] = *(const float4*)&proj[b * DIM + (j * 64 + lane) * 4];

    const float* sb = src + (size_t)b * SRC_LEN * DIM;
    float m = -INFINITY, l = 0.f;
    float c[16];
#pragma unroll
    for (int i = 0; i < 16; ++i) c[i] = 0.f;

    for (int it = 0; it < CHUNK / 4; ++it) {
        const int s = s0 + it * 4 + wave;
        if (s < len) {
            const float* row = sb + (size_t)s * DIM;
            float4 v[4];
#pragma unroll
            for (int j = 0; j < 4; ++j)
                v[j] = *(const float4*)&row[(j * 64 + lane) * 4];
            float sc = 0.f;
#pragma unroll
            for (int j = 0; j < 4; ++j)
                sc += v[j].x * pj[j].x + v[j].y * pj[j].y + v[j].z * pj[j].z + v[j].w * pj[j].w;
            sc = wave_reduce_sum(sc);
            if (lane == 0) scores[b * SRC_LEN + s] = sc;
            const float mn = fmaxf(m, sc);
            const float scale = __expf(m - mn);   // m=-inf -> 0, safe
            const float w = __expf(sc - mn);
            l = l * scale + w;
#pragma unroll
            for (int j = 0; j < 4; ++j) {
                c[j * 4 + 0] = c[j * 4 + 0] * scale + w * v[j].x;
                c[j * 4 + 1] = c[j * 4 + 1] * scale + w * v[j].y;
                c[j * 4 + 2] = c[j * 4 + 2] * scale + w * v[j].z;
                c[j * 4 + 3] = c[j * 4 + 3] * scale + w * v[j].w;
            }
            m = mn;
        } else {
            if (lane == 0) scores[b * SRC_LEN + s] = 0.f;  // masked; align kernel zeroes it
        }
    }

    // combine the block's 4 waves
    __shared__ float s_c[4][1024];
    __shared__ float s_ml[4][2];
#pragma unroll
    for (int j = 0; j < 4; ++j)
        *(float4*)&s_c[wave][(j * 64 + lane) * 4] =
            make_float4(c[j * 4 + 0], c[j * 4 + 1], c[j * 4 + 2], c[j * 4 + 3]);
    if (lane == 0) { s_ml[wave][0] = m; s_ml[wave][1] = l; }
    __syncthreads();

    const int t = threadIdx.x;
    float M = fmaxf(fmaxf(s_ml[0][0], s_ml[1][0]), fmaxf(s_ml[2][0], s_ml[3][0]));
    float L = 0.f;
    float4 acc = make_float4(0.f, 0.f, 0.f, 0.f);
#pragma unroll
    for (int wv = 0; wv < 4; ++wv) {
        const float mw = s_ml[wv][0];
        const float e = (mw == -INFINITY) ? 0.f : __expf(mw - M);  // avoid inf-inf NaN
        L += e * s_ml[wv][1];
        float4 cv = *(const float4*)&s_c[wv][t * 4];
        acc.x += e * cv.x; acc.y += e * cv.y; acc.z += e * cv.z; acc.w += e * cv.w;
    }
    if (t == 0) { part_ml[2 * blk] = M; part_ml[2 * blk + 1] = L; }
    *(float4*)&part_c[(size_t)blk * DIM + t * 4] = acc;
}

// ---------------- kernel 3: merge partials, write align, write c ------------
// grid 32 blocks (one per batch), 256 threads.
__global__ __launch_bounds__(256) void k_merge(const float* __restrict__ part_ml,
                                               const float* __restrict__ part_c,
                                               const float* __restrict__ scores,
                                               const int* __restrict__ lens,
                                               float* __restrict__ c_ws,
                                               float* __restrict__ out_align) {
    const int b = blockIdx.x;
    const int t = threadIdx.x;
    float M = -INFINITY;
#pragma unroll
    for (int i = 0; i < NCHUNK; ++i)
        M = fmaxf(M, part_ml[2 * (b * NCHUNK + i)]);
    float e[NCHUNK];
    float L = 0.f;
#pragma unroll
    for (int i = 0; i < NCHUNK; ++i) {
        const float mi = part_ml[2 * (b * NCHUNK + i)];
        e[i] = (mi == -INFINITY) ? 0.f : __expf(mi - M);
        L += e[i] * part_ml[2 * (b * NCHUNK + i) + 1];
    }
    const float invL = 1.f / L;
    float4 acc = make_float4(0.f, 0.f, 0.f, 0.f);
    for (int i = 0; i < NCHUNK; ++i) {
        float4 cv = *(const float4*)&part_c[(size_t)(b * NCHUNK + i) * DIM + t * 4];
        acc.x += e[i] * cv.x; acc.y += e[i] * cv.y; acc.z += e[i] * cv.z; acc.w += e[i] * cv.w;
    }
    acc.x *= invL; acc.y *= invL; acc.z *= invL; acc.w *= invL;
    *(float4*)&c_ws[b * DIM + t * 4] = acc;

    const int len = lens[b];
    for (int s = t; s < SRC_LEN; s += 256) {
        float a = 0.f;
        if (s < len) a = __expf(scores[b * SRC_LEN + s] - M) * invL;
        out_align[b * SRC_LEN + s] = a;
    }
}

// ---------------- kernel 4: attn_h = [c, tgt] @ Wo^T ------------------------
// grid 64 blocks (d-chunks of 16), 256 threads. Wo (8 MB) read exactly once.
__global__ __launch_bounds__(256) void k_out(const float* __restrict__ c_ws,
                                             const float* __restrict__ tgt,
                                             const float* __restrict__ Wo,
                                             float* __restrict__ out) {
    __shared__ float ct[32 * 257];  // padded
    __shared__ float wt[16 * 256];
    const int t = threadIdx.x;
    const int d0 = blockIdx.x * 16;
    const int b = t & 31;
    const int dg = t >> 5;          // 0..7, owns 2 d's
    float acc0 = 0.f, acc1 = 0.f;
    for (int k0 = 0; k0 < 2 * DIM; k0 += 256) {
        __syncthreads();
        for (int i = 0; i < 32; ++i) {
            const int k = k0 + t;
            ct[i * 257 + t] = (k < DIM) ? c_ws[i * DIM + k] : tgt[i * DIM + (k - DIM)];
        }
        for (int i = 0; i < 16; ++i)
            wt[i * 256 + t] = Wo[(size_t)(d0 + i) * (2 * DIM) + k0 + t];
        __syncthreads();
        for (int kk = 0; kk < 256; ++kk) {
            const float cv = ct[b * 257 + kk];
            acc0 += cv * wt[(dg * 2 + 0) * 256 + kk];
            acc1 += cv * wt[(dg * 2 + 1) * 256 + kk];
        }
    }
    out[b * DIM + d0 + dg * 2 + 0] = acc0;
    out[b * DIM + d0 + dg * 2 + 1] = acc1;
}

extern "C" void kernel_launch(void* const* d_in, const int* in_sizes, int n_in,
                              void* d_out, int out_size, void* d_ws, size_t ws_size,
                              hipStream_t stream) {
    const float* src = (const float*)d_in[0];   // (32, 2048, 1024)
    const float* tgt = (const float*)d_in[1];   // (32, 1, 1024)
    const float* Wg  = (const float*)d_in[2];   // (1024, 1024)
    const float* Wo  = (const float*)d_in[3];   // (1024, 2048)
    const int*   len = (const int*)d_in[4];     // (32,)
    float* out = (float*)d_out;                 // attn_h [0,32768) ++ align [32768,98304)

    float* ws = (float*)d_ws;
    float* proj    = ws;                              // 32*1024
    float* scores  = proj + BZ * DIM;                 // 32*2048
    float* part_ml = scores + BZ * SRC_LEN;           // 1024*2
    float* part_c  = part_ml + BZ * NCHUNK * 2;       // 1024*1024
    float* c_ws    = part_c + (size_t)BZ * NCHUNK * DIM;  // 32*1024

    k_proj <<<32,            256, 0, stream>>>(tgt, Wg, proj);
    k_flash<<<BZ * NCHUNK,   256, 0, stream>>>(src, proj, len, scores, part_ml, part_c);
    k_merge<<<BZ,            256, 0, stream>>>(part_ml, part_c, scores, len, c_ws, out + BZ * DIM);
    k_out  <<<DIM / 16,      256, 0, stream>>>(c_ws, tgt, Wo, out);
}